// Round 10
// baseline (4313.926 us; speedup 1.0000x reference)
//
#include <hip/hip_runtime.h>

// ---------------------------------------------------------------------------
// GenomeDecoder, R12: boundary-count minimization via REPLICATION.
// Ledger model (R2-R9): total = kernels + ~70us x boundaries (+~25 fixed).
// In-kernel cross-block sync is ruled out (R5/R7/R8: cg-sync and custom
// backoff barriers both cost >=150us/sync in L2-inv fences + refetch).
// Narrow-grid fronts are ruled out (R3/R6: latency chains).  So: each
// consumer block RECOMPUTES its producers' work (front is ~14 MMAC/batch,
// replication x4 is ~free at 64-wide):
//   L1 k_pre (128 blk x 512):
//      blk 0-63  (b,head): embed -> qkv+attn l0 ALL heads -> ao+ffn+LN l0
//                ALL 16 tokens (LDS) -> qkv+attn l1 OWN head -> AO(l1);
//                head0 writes HB(l1-in)
//      blk 64-127: prepm, 16 rows each (R7-verified 512-thread form)
//   L2 k_chain (16 blk): ao_ffn(l1) 16-token prologue (LDS) -> latent ->
//                gi0 -> R9 chain body verbatim
//   L3 k_epi (1028 blk): verbatim
// 3 launches / 2 boundaries (R9 had 5).  Chain math unchanged: int8 M
// (per-row scale) x int8 h broadcast via mfma_i32_16x16x64_i8, parity-split
// gates, exact int32 accumulate.
// ---------------------------------------------------------------------------

typedef unsigned int uint_t;
typedef int v4i __attribute__((ext_vector_type(4)));

// ---- workspace layout (4-byte slot indices) ----
static constexpr size_t WS_HB   = 0;        // 16*16*256  (post-l0 h)
static constexpr size_t WS_AO   = 262144;   // 16*16*256  (attn-out l1)
static constexpr size_t WS_CV   = 606208;   // 1024 fused-bias consts
static constexpr size_t WS_MS   = 607232;   // 1024 per-row scales
static constexpr size_t WS_M8   = 608256;   // 1024*64 dwords packed int8 M
static constexpr size_t WS_HSEQ = 673792;   // 1028*16*256 floats

__device__ inline float sigf(float x){
    return __builtin_amdgcn_rcpf(1.0f + __builtin_amdgcn_exp2f(-1.442695041f*x));
}
__device__ inline float tanh_fast(float x){
    return 1.0f - 2.0f*__builtin_amdgcn_rcpf(1.0f + __builtin_amdgcn_exp2f(2.885390082f*x));
}

// ======================= L1: mid (0-63) || prepm (64-127) ==================

__global__ __launch_bounds__(512) void k_pre(
    const float* gs, const float* eW, const float* eb,
    const float* qkvW, const float* qkvb,
    const float* aoW, const float* aob,
    const float* g1, const float* b1, const float* g2, const float* b2v,
    const float* W1, const float* fb1, const float* W2, const float* fb2,
    const float* Wih, const float* Whh, const float* bih, const float* bhh,
    const float* outW, const float* outb, float* ws)
{
    int tid = threadIdx.x;

    if(blockIdx.x >= 64){
        // ---------------- prepm, rows [pb*16, pb*16+16) (R7-verified) ------
        __shared__ float wrow[512];        // [2][256]
        __shared__ float redf[32];
        __shared__ signed char q8[512];    // [2][256]
        int pb = blockIdx.x - 64;
        int rh = tid>>8, c = tid&255, wv = tid>>6;
        for(int it=0; it<8; ++it){
            int r = pb*16 + it*2 + rh;
            bool hasA = (r < 768);
            wrow[rh*256+c] = hasA ? Wih[(size_t)r*256+c] : 0.0f;
            __syncthreads();
            float m;
            if(hasA){
                float a = 0.f;
                for(int k=0;k<256;++k) a += wrow[rh*256+k]*outW[(size_t)k*256+c];
                if(r<512) a += Whh[(size_t)r*256+c];
                m = a;
            } else {
                m = Whh[(size_t)(r-256)*256+c];
            }
            float pv = wrow[rh*256+c]*outb[c];
            for(int mk=1; mk<64; mk<<=1) pv += __shfl_xor(pv, mk);
            if((tid&63)==0) redf[wv] = pv;
            __syncthreads();
            if(c==0){
                float cs = redf[rh*4+0]+redf[rh*4+1]+redf[rh*4+2]+redf[rh*4+3];
                float cv;
                if(r<512)       cv = cs + bih[r] + bhh[r];
                else if(r<768)  cv = cs + bih[r];
                else            cv = bhh[r-256];
                ws[WS_CV + r] = cv;
            }
            float av = fabsf(m);
            for(int mk=1; mk<64; mk<<=1) av = fmaxf(av, __shfl_xor(av, mk));
            if((tid&63)==0) redf[16+wv] = av;
            __syncthreads();
            float rowmax = fmaxf(fmaxf(redf[16+rh*4],redf[17+rh*4]),
                                 fmaxf(redf[18+rh*4],redf[19+rh*4]));
            float inv = rowmax>0.f ? 127.0f/rowmax : 0.0f;
            q8[rh*256+c] = (signed char)__float2int_rn(m*inv);
            if(c==0) ws[WS_MS + r] = rowmax>0.f ? rowmax*(1.0f/(127.0f*127.0f)) : 0.0f;
            __syncthreads();
            if(c<64){
                uint_t u = ((uint_t)(unsigned char)q8[rh*256+4*c  ])
                         | ((uint_t)(unsigned char)q8[rh*256+4*c+1] << 8)
                         | ((uint_t)(unsigned char)q8[rh*256+4*c+2] << 16)
                         | ((uint_t)(unsigned char)q8[rh*256+4*c+3] << 24);
                ((uint_t*)ws)[WS_M8 + (size_t)r*64 + c] = u;
            }
            __syncthreads();
        }
        return;
    }

    // ---------------- mid block (b, hh): full l0 + own-head l1 -------------
    __shared__ float s_h[16][256];         // h (embed -> post-l0)
    __shared__ float s_qkv[3][16][64];     // one head's q/k/v
    __shared__ float s_sc[16][16];
    __shared__ float s_ao[16][256];        // attn-out l0, all heads
    __shared__ float s_f1[2][1024];
    __shared__ float s_hx[2][256];
    __shared__ float s_red[2][256];

    int b = blockIdx.x>>2, hh = blockIdx.x&3;

    // embed -> s_h
    for(int u=tid; u<4096; u+=512){
        int s=u>>8, i=u&255;
        const float* g = gs + (b*16+s)*16;
        float acc = eb[i];
#pragma unroll
        for(int d=0;d<16;++d) acc += g[d]*eW[i*16+d];
        s_h[s][i] = acc;
    }
    __syncthreads();

    // qkv + attn, layer 0, ALL 4 heads (replicated x4 across sibling blocks)
    for(int h2=0; h2<4; ++h2){
        if(tid<192){
            int p = tid>>6, d = tid&63;
            int row = p*256 + h2*64 + d;          // l=0
            const float* wr = qkvW + (size_t)row*256;
            float bias = qkvb[row];
            float acc[16];
#pragma unroll
            for(int s=0;s<16;++s) acc[s]=bias;
            for(int k=0;k<256;k+=4){
                float4 w4 = *(const float4*)(wr+k);
#pragma unroll
                for(int s=0;s<16;++s){
                    float4 h4 = *(const float4*)&s_h[s][k];
                    acc[s] += w4.x*h4.x + w4.y*h4.y + w4.z*h4.z + w4.w*h4.w;
                }
            }
#pragma unroll
            for(int s=0;s<16;++s) s_qkv[p][s][d] = acc[s];
        }
        __syncthreads();
        if(tid<256){
            int s = tid>>4, t = tid&15;
            float a=0.f;
#pragma unroll
            for(int d=0; d<64; ++d) a += s_qkv[0][s][d]*s_qkv[1][t][d];
            s_sc[s][t] = a*0.125f;
        }
        __syncthreads();
        if(tid<16){
            int r=tid;
            float m=-1e30f;
#pragma unroll
            for(int tt=0;tt<16;++tt) m=fmaxf(m,s_sc[r][tt]);
            float e[16]; float sum=0.f;
#pragma unroll
            for(int tt=0;tt<16;++tt){ e[tt]=__expf(s_sc[r][tt]-m); sum+=e[tt]; }
            float inv=1.0f/sum;
#pragma unroll
            for(int tt=0;tt<16;++tt) s_sc[r][tt]=e[tt]*inv;
        }
        __syncthreads();
        for(int u=tid; u<1024; u+=512){
            int s=u>>6, d=u&63;
            float o=0.f;
#pragma unroll
            for(int t2=0;t2<16;++t2) o += s_sc[s][t2]*s_qkv[2][t2][d];
            s_ao[s][h2*64 + d] = o;
        }
        __syncthreads();
    }

    // ao-matvec + LN1 + ffn1 + ffn2 + LN2, layer 0, all 16 tokens (2/iter)
    for(int it=0; it<8; ++it){
        int tk = tid>>8, i = tid&255, s = it*2+tk;
        const float* wr = aoW + (size_t)(0*256+i)*256;
        float acc = aob[0*256+i];
        for(int k=0;k<256;k+=4){
            float4 w4 = *(const float4*)(wr+k);
            float4 a4 = *(const float4*)&s_ao[s][k];
            acc += w4.x*a4.x + w4.y*a4.y + w4.z*a4.z + w4.w*a4.w;
        }
        float x = s_h[s][i] + acc;
        s_red[tk][i]=x; __syncthreads();
        for(int off=128;off>0;off>>=1){ if(i<off) s_red[tk][i]+=s_red[tk][i+off]; __syncthreads(); }
        float mn = s_red[tk][0]*(1.0f/256.0f); __syncthreads();
        float d = x-mn;
        s_red[tk][i]=d*d; __syncthreads();
        for(int off=128;off>0;off>>=1){ if(i<off) s_red[tk][i]+=s_red[tk][i+off]; __syncthreads(); }
        float vv = s_red[tk][0]*(1.0f/256.0f);
        float h1 = (d / sqrtf(vv+1e-5f))*g1[0*256+i] + b1[0*256+i];
        __syncthreads();
        s_hx[tk][i] = h1;
        __syncthreads();
#pragma unroll
        for(int jj=0;jj<4;++jj){
            int j = jj*256 + i;
            const float* w1r = W1 + (size_t)(0*1024+j)*256;
            float a1 = fb1[0*1024+j];
            for(int k=0;k<256;k+=4){
                float4 w4 = *(const float4*)(w1r+k);
                float4 h4 = *(const float4*)&s_hx[tk][k];
                a1 += w4.x*h4.x + w4.y*h4.y + w4.z*h4.z + w4.w*h4.w;
            }
            s_f1[tk][j] = fmaxf(a1, 0.0f);
        }
        __syncthreads();
        const float* w2r = W2 + (size_t)(0*256+i)*1024;
        float a2 = fb2[0*256+i];
        for(int k=0;k<1024;k+=4){
            float4 w4 = *(const float4*)(w2r+k);
            float4 h4 = *(const float4*)&s_f1[tk][k];
            a2 += w4.x*h4.x + w4.y*h4.y + w4.z*h4.z + w4.w*h4.w;
        }
        float x2 = h1 + a2;
        s_red[tk][i]=x2; __syncthreads();
        for(int off=128;off>0;off>>=1){ if(i<off) s_red[tk][i]+=s_red[tk][i+off]; __syncthreads(); }
        float mn2 = s_red[tk][0]*(1.0f/256.0f); __syncthreads();
        float d2 = x2-mn2;
        s_red[tk][i]=d2*d2; __syncthreads();
        for(int off=128;off>0;off>>=1){ if(i<off) s_red[tk][i]+=s_red[tk][i+off]; __syncthreads(); }
        float vv2 = s_red[tk][0]*(1.0f/256.0f);
        float y2 = d2 / sqrtf(vv2+1e-5f);
        s_h[s][i] = y2*g2[0*256+i] + b2v[0*256+i];    // own element: safe
        __syncthreads();
    }

    // qkv + attn, layer 1, OWN head -> ws AO; head 0 writes HB(l1-in)
    if(tid<192){
        int p = tid>>6, d = tid&63;
        int row = 768 + p*256 + hh*64 + d;            // l=1
        const float* wr = qkvW + (size_t)row*256;
        float bias = qkvb[row];
        float acc[16];
#pragma unroll
        for(int s=0;s<16;++s) acc[s]=bias;
        for(int k=0;k<256;k+=4){
            float4 w4 = *(const float4*)(wr+k);
#pragma unroll
            for(int s=0;s<16;++s){
                float4 h4 = *(const float4*)&s_h[s][k];
                acc[s] += w4.x*h4.x + w4.y*h4.y + w4.z*h4.z + w4.w*h4.w;
            }
        }
#pragma unroll
        for(int s=0;s<16;++s) s_qkv[p][s][d] = acc[s];
    }
    __syncthreads();
    if(tid<256){
        int s = tid>>4, t = tid&15;
        float a=0.f;
#pragma unroll
        for(int d=0; d<64; ++d) a += s_qkv[0][s][d]*s_qkv[1][t][d];
        s_sc[s][t] = a*0.125f;
    }
    __syncthreads();
    if(tid<16){
        int r=tid;
        float m=-1e30f;
#pragma unroll
        for(int tt=0;tt<16;++tt) m=fmaxf(m,s_sc[r][tt]);
        float e[16]; float sum=0.f;
#pragma unroll
        for(int tt=0;tt<16;++tt){ e[tt]=__expf(s_sc[r][tt]-m); sum+=e[tt]; }
        float inv=1.0f/sum;
#pragma unroll
        for(int tt=0;tt<16;++tt) s_sc[r][tt]=e[tt]*inv;
    }
    __syncthreads();
    for(int u=tid; u<1024; u+=512){
        int s=u>>6, d=u&63;
        float o=0.f;
#pragma unroll
        for(int t2=0;t2<16;++t2) o += s_sc[s][t2]*s_qkv[2][t2][d];
        ws[WS_AO + (size_t)(b*16+s)*256 + hh*64 + d] = o;
    }
    if(hh==0){
        for(int u=tid; u<4096; u+=512)
            ws[WS_HB + (size_t)(b*16+(u>>8))*256 + (u&255)] = s_h[u>>8][u&255];
    }
}

// ============= L2: chain (ao_ffn l1 + latent + gi0 prologue) ===============

__global__ __launch_bounds__(512,2) void k_chain(
    const float* aoW, const float* aob, const float* g1, const float* b1,
    const float* W1, const float* fb1, const float* W2, const float* fb2,
    const float* g2, const float* b2v,
    const float* Wih, const float* bih, const float* bhh, float* ws)
{
    __shared__ alignas(16) signed char h8[2][256];
    __shared__ float s_hf[16][256];        // post-l1 h
    __shared__ float s_f1[2][1024];
    __shared__ float s_hx[2][256];
    __shared__ float s_red[2][256];
    __shared__ float latl[256];
    __shared__ float gi0l[768];
    int tid = threadIdx.x;
    int b   = blockIdx.x;

    // ---- ao_ffn layer 1, 16 tokens (2/iter) -> s_hf ----
    for(int it=0; it<8; ++it){
        int tk = tid>>8, i = tid&255, s = it*2+tk;
        int bs = b*16 + s;
        s_hx[tk][i] = ws[WS_AO + (size_t)bs*256 + i];
        float hb = ws[WS_HB + (size_t)bs*256 + i];
        __syncthreads();
        const float* wr = aoW + (size_t)(1*256+i)*256;
        float acc = aob[1*256+i];
        for(int k=0;k<256;k+=4){
            float4 w4 = *(const float4*)(wr+k);
            float4 a4 = *(const float4*)&s_hx[tk][k];
            acc += w4.x*a4.x + w4.y*a4.y + w4.z*a4.z + w4.w*a4.w;
        }
        float x = hb + acc;
        s_red[tk][i]=x; __syncthreads();
        for(int off=128;off>0;off>>=1){ if(i<off) s_red[tk][i]+=s_red[tk][i+off]; __syncthreads(); }
        float mn = s_red[tk][0]*(1.0f/256.0f); __syncthreads();
        float d = x-mn;
        s_red[tk][i]=d*d; __syncthreads();
        for(int off=128;off>0;off>>=1){ if(i<off) s_red[tk][i]+=s_red[tk][i+off]; __syncthreads(); }
        float vv = s_red[tk][0]*(1.0f/256.0f);
        float h1 = (d / sqrtf(vv+1e-5f))*g1[1*256+i] + b1[1*256+i];
        __syncthreads();
        s_hx[tk][i] = h1;
        __syncthreads();
#pragma unroll
        for(int jj=0;jj<4;++jj){
            int j = jj*256 + i;
            const float* w1r = W1 + (size_t)(1*1024+j)*256;
            float a1 = fb1[1*1024+j];
            for(int k=0;k<256;k+=4){
                float4 w4 = *(const float4*)(w1r+k);
                float4 h4 = *(const float4*)&s_hx[tk][k];
                a1 += w4.x*h4.x + w4.y*h4.y + w4.z*h4.z + w4.w*h4.w;
            }
            s_f1[tk][j] = fmaxf(a1, 0.0f);
        }
        __syncthreads();
        const float* w2r = W2 + (size_t)(1*256+i)*1024;
        float a2 = fb2[1*256+i];
        for(int k=0;k<1024;k+=4){
            float4 w4 = *(const float4*)(w2r+k);
            float4 h4 = *(const float4*)&s_f1[tk][k];
            a2 += w4.x*h4.x + w4.y*h4.y + w4.z*h4.z + w4.w*h4.w;
        }
        float x2 = h1 + a2;
        s_red[tk][i]=x2; __syncthreads();
        for(int off=128;off>0;off>>=1){ if(i<off) s_red[tk][i]+=s_red[tk][i+off]; __syncthreads(); }
        float mn2 = s_red[tk][0]*(1.0f/256.0f); __syncthreads();
        float d2 = x2-mn2;
        s_red[tk][i]=d2*d2; __syncthreads();
        for(int off=128;off>0;off>>=1){ if(i<off) s_red[tk][i]+=s_red[tk][i+off]; __syncthreads(); }
        float vv2 = s_red[tk][0]*(1.0f/256.0f);
        float y2 = d2 / sqrtf(vv2+1e-5f);
        s_hf[s][i] = y2*g2[1*256+i] + b2v[1*256+i];
        __syncthreads();
    }

    // ---- latent + gi0 ----
    if(tid<256){
        float a=0.f;
#pragma unroll
        for(int s=0;s<16;++s) a += s_hf[s][tid];
        latl[tid] = a*(1.0f/16.0f);
    }
    __syncthreads();
    for(int j=tid; j<768; j+=512){
        const float* wr = Wih + (size_t)j*256;
        float a = bih[j];
        for(int k=0;k<256;k+=4){
            float4 w4=*(const float4*)(wr+k);
            float4 l4=*(const float4*)&latl[k];
            a += w4.x*l4.x + w4.y*l4.y + w4.z*l4.z + w4.w*l4.w;
        }
        gi0l[j] = a;
    }
    __syncthreads();

    // ---- chain body (R9 verbatim) ----
    int l   = tid & 63;
    int w   = tid >> 6;
    int col = l & 15;
    int grp = l >> 4;
    int par = grp & 1;
    int ge  = w*32 + par*16 + col;

    const uint_t* Mdw = (const uint_t*)ws + WS_M8;
    v4i wf[8][4];
#pragma unroll
    for(int s=0;s<4;++s){
#pragma unroll
        for(int half=0; half<2; ++half){
            int f = s*2 + half;
            int row = s*256 + w*32 + half*16 + col;
            const uint_t* src = Mdw + (size_t)row*64 + grp*4;
#pragma unroll
            for(int kt=0;kt<4;++kt)
                wf[f][kt] = *(const v4i*)(src + kt*16);
        }
    }
    float Cs[4], MSs[4];
#pragma unroll
    for(int s=0;s<4;++s){
        int row = s*256 + ge;
        Cs[s]  = ws[WS_CV + row];
        MSs[s] = ws[WS_MS + row];
    }

    float r0 = sigf(gi0l[ge]     + bhh[ge]);
    float z0 = sigf(gi0l[256+ge] + bhh[256+ge]);
    float n0 = tanh_fast(gi0l[512+ge] + r0*bhh[512+ge]);
    float hp = (1.0f-z0)*n0;

    float* hsp = ws + WS_HSEQ + (size_t)b*256;
    if(grp < 2){
        h8[0][w*32 + (l&31)] = (signed char)__float2int_rn(hp*127.0f);
        hsp[w*32 + (l&31)] = hp;
    }
    asm volatile("s_waitcnt lgkmcnt(0)" ::: "memory");
    __builtin_amdgcn_s_barrier();
    asm volatile("" ::: "memory");

    const v4i vzero = {0,0,0,0};
    int po = 0;
    for(int t=1; t<1028; ++t){
        hsp += 4096;
        v4i af[4];
#pragma unroll
        for(int kt=0;kt<4;++kt)
            af[kt] = *(const v4i*)&h8[po][kt*64 + grp*16];
        v4i acc[8];
#pragma unroll
        for(int f=0;f<8;++f){
            acc[f] = __builtin_amdgcn_mfma_i32_16x16x64_i8(af[0], wf[f][0], vzero, 0,0,0);
#pragma unroll
            for(int kt=1;kt<4;++kt)
                acc[f] = __builtin_amdgcn_mfma_i32_16x16x64_i8(af[kt], wf[f][kt], acc[f], 0,0,0);
        }
        int a_r = par ? acc[1][0] : acc[0][0];
        int a_z = par ? acc[3][0] : acc[2][0];
        int a_n = par ? acc[5][0] : acc[4][0];
        int a_h = par ? acc[7][0] : acc[6][0];
        float yr = MSs[0]*(float)a_r + Cs[0];
        float yz = MSs[1]*(float)a_z + Cs[1];
        float yn = MSs[2]*(float)a_n + Cs[2];
        float yh = MSs[3]*(float)a_h + Cs[3];
        float rr = sigf(yr);
        float zz = sigf(yz);
        float nn = tanh_fast(yn + rr*yh);
        hp = (1.0f-zz)*nn + zz*hp;
        if(grp < 2){
            h8[po^1][w*32 + (l&31)] = (signed char)__float2int_rn(hp*127.0f);
            hsp[w*32 + (l&31)] = hp;
        }
        asm volatile("s_waitcnt lgkmcnt(0)" ::: "memory");
        __builtin_amdgcn_s_barrier();
        asm volatile("" ::: "memory");
        po ^= 1;
    }
}

// ======================= L3: epilogue GEMM (wide) ==========================

__global__ __launch_bounds__(256) void k_epi(const float* outW, const float* outb,
                                             const float* ws, float* out){
    __shared__ float ht[16][256];
    int t = blockIdx.x, j = threadIdx.x;
    for(int idx=j; idx<4096; idx+=256)
        ht[idx>>8][idx&255] = ws[WS_HSEQ + (size_t)t*4096 + idx];
    __syncthreads();
    const float* wr = outW + (size_t)j*256;
    float bias = outb[j];
    float acc[16];
#pragma unroll
    for(int bb=0;bb<16;++bb) acc[bb]=bias;
    for(int k=0;k<256;k+=4){
        float4 w4 = *(const float4*)(wr+k);
#pragma unroll
        for(int bb=0;bb<16;++bb)
            acc[bb] += w4.x*ht[bb][k]+w4.y*ht[bb][k+1]+w4.z*ht[bb][k+2]+w4.w*ht[bb][k+3];
    }
#pragma unroll
    for(int bb=0;bb<16;++bb)
        out[(size_t)bb*263168 + (size_t)t*256 + j] = acc[bb];
}

// ======================= launch ============================================

extern "C" void kernel_launch(void* const* d_in, const int* in_sizes, int n_in,
                              void* d_out, int out_size, void* d_ws, size_t ws_size,
                              hipStream_t stream){
    const float* gs   = (const float*)d_in[0];
    const float* eW   = (const float*)d_in[1];
    const float* eb   = (const float*)d_in[2];
    const float* qkvW = (const float*)d_in[3];
    const float* qkvb = (const float*)d_in[4];
    const float* aoW  = (const float*)d_in[5];
    const float* aob  = (const float*)d_in[6];
    const float* g1   = (const float*)d_in[7];
    const float* b1   = (const float*)d_in[8];
    const float* g2   = (const float*)d_in[9];
    const float* b2   = (const float*)d_in[10];
    const float* W1   = (const float*)d_in[11];
    const float* fb1  = (const float*)d_in[12];
    const float* W2   = (const float*)d_in[13];
    const float* fb2  = (const float*)d_in[14];
    const float* Wih  = (const float*)d_in[15];
    const float* Whh  = (const float*)d_in[16];
    const float* bih  = (const float*)d_in[17];
    const float* bhh  = (const float*)d_in[18];
    const float* outW = (const float*)d_in[19];
    const float* outb = (const float*)d_in[20];
    float* ws  = (float*)d_ws;
    float* out = (float*)d_out;

    k_pre  <<<128,512,0,stream>>>(gs,eW,eb,qkvW,qkvb,aoW,aob,g1,b1,g2,b2,
                                  W1,fb1,W2,fb2,Wih,Whh,bih,bhh,outW,outb,ws);
    k_chain<<<16,512,0,stream>>>(aoW,aob,g1,b1,W1,fb1,W2,fb2,g2,b2,
                                 Wih,bih,bhh,ws);
    k_epi  <<<1028,256,0,stream>>>(outW,outb,ws,out);
}

// Round 11
// 2679.924 us; speedup vs baseline: 1.6097x; 1.6097x over previous
//
#include <hip/hip_runtime.h>

// ---------------------------------------------------------------------------
// GenomeDecoder, R13: R9 skeleton (best, 1088us) + ONE re-fixed merge.
// R10 post-mortem: merged chain spilled (FETCH 132MB = per-step scratch
// reloads) because (a) __launch_bounds__(512,2) capped VGPR at 128 for no
// benefit (16 blocks / 256 CUs -> occupancy irrelevant) and (b) the compiler
// hoisted the 128-VGPR wf[] global loads ABOVE the ao_ffn prologue (no dep),
// keeping them live through it.  Fixes: launch_bounds(512) uncapped + an
// asm memory fence pinning wf loads after the prologue.  R10's replicated
// k_pre (42ms outlier, 61KB LDS) is fully reverted to R9's form.
// Launches (5, was 6 in R9):
//   L1 k_pre      1088 blk: embed+qkv_attn(l0) (0-63) || prepm 1-row (64-1087)
//   L2 k_ao_ffn   256 blk, l=0
//   L3 k_qkv_attn 64 blk, l=1
//   L4 k_chain    16 blk: ao_ffn(l1)+latent+gi0 prologue -> chain body
//   L5 k_epi      1028 blk
// Chain math unchanged: int8 M (per-row scale) x int8 h broadcast via
// mfma_i32_16x16x64_i8, parity-split gates, exact int32 accumulate.
// ---------------------------------------------------------------------------

typedef unsigned int uint_t;
typedef int v4i __attribute__((ext_vector_type(4)));

// ---- workspace layout (4-byte slot indices) ----
static constexpr size_t WS_HB   = 0;        // 16*16*256
static constexpr size_t WS_AO   = 262144;   // 16*16*256
static constexpr size_t WS_CV   = 606208;   // 1024 fused-bias consts
static constexpr size_t WS_MS   = 607232;   // 1024 per-row scales
static constexpr size_t WS_M8   = 608256;   // 1024*64 dwords packed int8 M
static constexpr size_t WS_HSEQ = 673792;   // 1028*16*256 floats

__device__ inline float sigf(float x){
    return __builtin_amdgcn_rcpf(1.0f + __builtin_amdgcn_exp2f(-1.442695041f*x));
}
__device__ inline float tanh_fast(float x){
    return 1.0f - 2.0f*__builtin_amdgcn_rcpf(1.0f + __builtin_amdgcn_exp2f(2.885390082f*x));
}

// ============== L1: [embed+qkv+attn l0] (blocks 0-63) || prepm (64-1087) ===

__global__ __launch_bounds__(256) void k_pre(
    const float* gs, const float* eW, const float* eb,
    const float* qkvW, const float* qkvb,
    const float* Wih, const float* Whh, const float* bih, const float* bhh,
    const float* outW, const float* outb, float* ws)
{
    __shared__ float s_h[16][256];
    __shared__ float s_qkv[3][16][64];
    __shared__ float s_sc[16][16];

    int tid = threadIdx.x;

    if(blockIdx.x >= 64){
        // ---------------- prepm row r (R4/R9 verbatim) ----------------
        __shared__ float wrow[256]; __shared__ float red[256];
        __shared__ signed char q8[256];
        int r = blockIdx.x - 64, c = tid;
        bool hasA = (r<768);
        wrow[c] = hasA ? Wih[(size_t)r*256+c] : 0.0f;
        __syncthreads();
        float m;
        if(hasA){
            float a=0.f;
            for(int k=0;k<256;++k) a += wrow[k]*outW[(size_t)k*256+c];
            if(r<512) a += Whh[(size_t)r*256+c];
            m=a;
        } else {
            m = Whh[(size_t)(r-256)*256+c];
        }
        red[c] = wrow[c]*outb[c];
        __syncthreads();
        for(int off=128;off>0;off>>=1){ if(c<off) red[c]+=red[c+off]; __syncthreads(); }
        if(c==0){
            float cv;
            if(r<512)       cv = red[0] + bih[r] + bhh[r];
            else if(r<768)  cv = red[0] + bih[r];
            else            cv = bhh[r-256];
            ws[WS_CV + r] = cv;
        }
        __syncthreads();
        red[c] = fabsf(m);
        __syncthreads();
        for(int off=128;off>0;off>>=1){ if(c<off) red[c]=fmaxf(red[c],red[c+off]); __syncthreads(); }
        float rowmax = red[0];
        float inv = rowmax>0.f ? 127.0f/rowmax : 0.0f;
        q8[c] = (signed char)__float2int_rn(m*inv);
        if(c==0) ws[WS_MS + r] = rowmax>0.f ? rowmax*(1.0f/(127.0f*127.0f)) : 0.0f;
        __syncthreads();
        if(c<64){
            uint_t u = ((uint_t)(unsigned char)q8[4*c  ])
                     | ((uint_t)(unsigned char)q8[4*c+1] << 8)
                     | ((uint_t)(unsigned char)q8[4*c+2] << 16)
                     | ((uint_t)(unsigned char)q8[4*c+3] << 24);
            ((uint_t*)ws)[WS_M8 + (size_t)r*64 + c] = u;
        }
        return;
    }

    // ---------------- embed (inline) + qkv + attention, (b,head), l=0 ------
    int b = blockIdx.x>>2, hh = blockIdx.x&3;

    {   // embed: thread i computes dim i for all 16 tokens of batch b
        int i = tid;
        float ew[16];
#pragma unroll
        for(int d=0;d<16;++d) ew[d] = eW[i*16+d];
        float bias = eb[i];
#pragma unroll
        for(int s=0;s<16;++s){
            const float* g = gs + (b*16+s)*16;
            float acc = bias;
#pragma unroll
            for(int d=0;d<16;++d) acc += g[d]*ew[d];
            s_h[s][i] = acc;
            if(hh==0) ws[WS_HB + (size_t)(b*16+s)*256 + i] = acc;
        }
    }
    __syncthreads();

    if(tid<192){
        int p = tid>>6, d = tid&63;           // p: 0=q 1=k 2=v
        int row = p*256 + hh*64 + d;          // l=0
        const float* wr = qkvW + (size_t)row*256;
        float bias = qkvb[row];
        float acc[16];
#pragma unroll
        for(int s=0;s<16;++s) acc[s]=bias;
        for(int k=0;k<256;k+=4){
            float4 w4 = *(const float4*)(wr+k);
#pragma unroll
            for(int s=0;s<16;++s){
                float4 h4 = *(const float4*)&s_h[s][k];
                acc[s] += w4.x*h4.x + w4.y*h4.y + w4.z*h4.z + w4.w*h4.w;
            }
        }
#pragma unroll
        for(int s=0;s<16;++s) s_qkv[p][s][d] = acc[s];
    }
    __syncthreads();
    {
        int s = tid>>4, t = tid&15;
        float a=0.f;
#pragma unroll
        for(int d=0; d<64; ++d) a += s_qkv[0][s][d]*s_qkv[1][t][d];
        s_sc[s][t] = a*0.125f;
    }
    __syncthreads();
    if(tid<16){
        int r=tid;
        float m=-1e30f;
#pragma unroll
        for(int tt=0;tt<16;++tt) m=fmaxf(m,s_sc[r][tt]);
        float e[16]; float sum=0.f;
#pragma unroll
        for(int tt=0;tt<16;++tt){ e[tt]=__expf(s_sc[r][tt]-m); sum+=e[tt]; }
        float inv=1.0f/sum;
#pragma unroll
        for(int tt=0;tt<16;++tt) s_sc[r][tt]=e[tt]*inv;
    }
    __syncthreads();
    for(int u=tid; u<1024; u+=256){
        int s=u>>6, d=u&63;
        float o=0.f;
#pragma unroll
        for(int t2=0;t2<16;++t2) o += s_sc[s][t2]*s_qkv[2][t2][d];
        ws[WS_AO + (size_t)(b*16+s)*256 + hh*64 + d] = o;
    }
}

// ======================= qkv + attention (layer 1) =========================

__global__ __launch_bounds__(256) void k_qkv_attn(const float* qkvW, const float* qkvb,
                                                  float* ws, int l){
    __shared__ float s_h[16][256];
    __shared__ float s_q[16][64], s_k[16][64], s_v[16][64];
    __shared__ float s_sc[16][16];
    int b = blockIdx.x>>2, hh = blockIdx.x&3;
    int tid = threadIdx.x;

    for(int u=tid; u<4096; u+=256)
        s_h[u>>8][u&255] = ws[WS_HB + (size_t)(b*16+(u>>8))*256 + (u&255)];
    __syncthreads();

    if(tid<192){
        int p = tid>>6, d = tid&63;
        int row = l*768 + p*256 + hh*64 + d;
        const float* wr = qkvW + (size_t)row*256;
        float bias = qkvb[row];
        float acc[16];
#pragma unroll
        for(int s=0;s<16;++s) acc[s]=bias;
        for(int k=0;k<256;k+=4){
            float4 w4 = *(const float4*)(wr+k);
#pragma unroll
            for(int s=0;s<16;++s){
                float4 h4 = *(const float4*)&s_h[s][k];
                acc[s] += w4.x*h4.x + w4.y*h4.y + w4.z*h4.z + w4.w*h4.w;
            }
        }
        float (*dst)[64] = (p==0) ? s_q : (p==1) ? s_k : s_v;
#pragma unroll
        for(int s=0;s<16;++s) dst[s][d] = acc[s];
    }
    __syncthreads();
    {
        int s = tid>>4, t = tid&15;
        float a=0.f;
#pragma unroll
        for(int d=0; d<64; ++d) a += s_q[s][d]*s_k[t][d];
        s_sc[s][t] = a*0.125f;
    }
    __syncthreads();
    if(tid<16){
        int r=tid;
        float m=-1e30f;
#pragma unroll
        for(int tt=0;tt<16;++tt) m=fmaxf(m,s_sc[r][tt]);
        float e[16]; float sum=0.f;
#pragma unroll
        for(int tt=0;tt<16;++tt){ e[tt]=__expf(s_sc[r][tt]-m); sum+=e[tt]; }
        float inv=1.0f/sum;
#pragma unroll
        for(int tt=0;tt<16;++tt) s_sc[r][tt]=e[tt]*inv;
    }
    __syncthreads();
    for(int u=tid; u<1024; u+=256){
        int s=u>>6, d=u&63;
        float o=0.f;
#pragma unroll
        for(int t2=0;t2<16;++t2) o += s_sc[s][t2]*s_v[t2][d];
        ws[WS_AO + (size_t)(b*16+s)*256 + hh*64 + d] = o;
    }
}

// ============ attn-out + LN1 + ffn1 + ffn2 + LN2, per (b,s), l=0 ===========

__global__ __launch_bounds__(256) void k_ao_ffn(
    const float* aoW, const float* aob, const float* g1, const float* b1,
    const float* W1, const float* fb1, const float* W2, const float* fb2,
    const float* g2, const float* b2v, float* ws, int l)
{
    __shared__ float s_x[256];
    __shared__ float s_f1[1024];
    __shared__ float red[256];
    int bs = blockIdx.x, i = threadIdx.x;

    s_x[i] = ws[WS_AO + (size_t)bs*256 + i];
    float hb = ws[WS_HB + (size_t)bs*256 + i];
    __syncthreads();

    const float* wr = aoW + (size_t)(l*256+i)*256;
    float acc = aob[l*256+i];
    for(int k=0;k<256;k+=4){
        float4 w4 = *(const float4*)(wr+k);
        float4 h4 = *(const float4*)&s_x[k];
        acc += w4.x*h4.x + w4.y*h4.y + w4.z*h4.z + w4.w*h4.w;
    }
    float x = hb + acc;
    red[i]=x; __syncthreads();
    for(int off=128;off>0;off>>=1){ if(i<off) red[i]+=red[i+off]; __syncthreads(); }
    float mn = red[0]*(1.0f/256.0f); __syncthreads();
    float d = x-mn;
    red[i]=d*d; __syncthreads();
    for(int off=128;off>0;off>>=1){ if(i<off) red[i]+=red[i+off]; __syncthreads(); }
    float vv = red[0]*(1.0f/256.0f);
    float h1 = (d / sqrtf(vv+1e-5f))*g1[l*256+i] + b1[l*256+i];
    __syncthreads();
    s_x[i] = h1;
    __syncthreads();

#pragma unroll
    for(int jj=0;jj<4;++jj){
        int j = jj*256 + i;
        const float* w1r = W1 + (size_t)(l*1024+j)*256;
        float a1 = fb1[l*1024+j];
        for(int k=0;k<256;k+=4){
            float4 w4 = *(const float4*)(w1r+k);
            float4 h4 = *(const float4*)&s_x[k];
            a1 += w4.x*h4.x + w4.y*h4.y + w4.z*h4.z + w4.w*h4.w;
        }
        s_f1[j] = fmaxf(a1, 0.0f);
    }
    __syncthreads();

    const float* w2r = W2 + (size_t)(l*256+i)*1024;
    float a2 = fb2[l*256+i];
    for(int k=0;k<1024;k+=4){
        float4 w4 = *(const float4*)(w2r+k);
        float4 h4 = *(const float4*)&s_f1[k];
        a2 += w4.x*h4.x + w4.y*h4.y + w4.z*h4.z + w4.w*h4.w;
    }
    float x2 = h1 + a2;
    red[i]=x2; __syncthreads();
    for(int off=128;off>0;off>>=1){ if(i<off) red[i]+=red[i+off]; __syncthreads(); }
    float mn2 = red[0]*(1.0f/256.0f); __syncthreads();
    float d2 = x2-mn2;
    red[i]=d2*d2; __syncthreads();
    for(int off=128;off>0;off>>=1){ if(i<off) red[i]+=red[i+off]; __syncthreads(); }
    float vv2 = red[0]*(1.0f/256.0f);
    float y2 = d2 / sqrtf(vv2+1e-5f);
    ws[WS_HB + (size_t)bs*256 + i] = y2*g2[l*256+i] + b2v[l*256+i];
}

// ============= L4: chain (ao_ffn l1 + latent + gi0 prologue) ===============
// __launch_bounds__(512): NO min-waves cap (16 blocks / 256 CUs, per-CU
// occupancy irrelevant) -> allocator gets up to 256 VGPR, no R10 spill.
// asm memory fence pins the 128-VGPR wf[] loads AFTER the prologue.

__global__ __launch_bounds__(512) void k_chain(
    const float* aoW, const float* aob, const float* g1, const float* b1,
    const float* W1, const float* fb1, const float* W2, const float* fb2,
    const float* g2, const float* b2v,
    const float* Wih, const float* bih, const float* bhh, float* ws)
{
    __shared__ alignas(16) signed char h8[2][256];
    __shared__ float s_hf[16][256];        // post-l1 h
    __shared__ float s_f1[2][1024];
    __shared__ float s_hx[2][256];
    __shared__ float s_red[2][256];
    __shared__ float latl[256];
    __shared__ float gi0l[768];
    int tid = threadIdx.x;
    int b   = blockIdx.x;

    // ---- ao_ffn layer 1, 16 tokens (2/iter) -> s_hf ----
    for(int it=0; it<8; ++it){
        int tk = tid>>8, i = tid&255, s = it*2+tk;
        int bs = b*16 + s;
        s_hx[tk][i] = ws[WS_AO + (size_t)bs*256 + i];
        float hb = ws[WS_HB + (size_t)bs*256 + i];
        __syncthreads();
        const float* wr = aoW + (size_t)(1*256+i)*256;
        float acc = aob[1*256+i];
        for(int k=0;k<256;k+=4){
            float4 w4 = *(const float4*)(wr+k);
            float4 a4 = *(const float4*)&s_hx[tk][k];
            acc += w4.x*a4.x + w4.y*a4.y + w4.z*a4.z + w4.w*a4.w;
        }
        float x = hb + acc;
        s_red[tk][i]=x; __syncthreads();
        for(int off=128;off>0;off>>=1){ if(i<off) s_red[tk][i]+=s_red[tk][i+off]; __syncthreads(); }
        float mn = s_red[tk][0]*(1.0f/256.0f); __syncthreads();
        float d = x-mn;
        s_red[tk][i]=d*d; __syncthreads();
        for(int off=128;off>0;off>>=1){ if(i<off) s_red[tk][i]+=s_red[tk][i+off]; __syncthreads(); }
        float vv = s_red[tk][0]*(1.0f/256.0f);
        float h1 = (d / sqrtf(vv+1e-5f))*g1[1*256+i] + b1[1*256+i];
        __syncthreads();
        s_hx[tk][i] = h1;
        __syncthreads();
#pragma unroll
        for(int jj=0;jj<4;++jj){
            int j = jj*256 + i;
            const float* w1r = W1 + (size_t)(1*1024+j)*256;
            float a1 = fb1[1*1024+j];
            for(int k=0;k<256;k+=4){
                float4 w4 = *(const float4*)(w1r+k);
                float4 h4 = *(const float4*)&s_hx[tk][k];
                a1 += w4.x*h4.x + w4.y*h4.y + w4.z*h4.z + w4.w*h4.w;
            }
            s_f1[tk][j] = fmaxf(a1, 0.0f);
        }
        __syncthreads();
        const float* w2r = W2 + (size_t)(1*256+i)*1024;
        float a2 = fb2[1*256+i];
        for(int k=0;k<1024;k+=4){
            float4 w4 = *(const float4*)(w2r+k);
            float4 h4 = *(const float4*)&s_f1[tk][k];
            a2 += w4.x*h4.x + w4.y*h4.y + w4.z*h4.z + w4.w*h4.w;
        }
        float x2 = h1 + a2;
        s_red[tk][i]=x2; __syncthreads();
        for(int off=128;off>0;off>>=1){ if(i<off) s_red[tk][i]+=s_red[tk][i+off]; __syncthreads(); }
        float mn2 = s_red[tk][0]*(1.0f/256.0f); __syncthreads();
        float d2 = x2-mn2;
        s_red[tk][i]=d2*d2; __syncthreads();
        for(int off=128;off>0;off>>=1){ if(i<off) s_red[tk][i]+=s_red[tk][i+off]; __syncthreads(); }
        float vv2 = s_red[tk][0]*(1.0f/256.0f);
        float y2 = d2 / sqrtf(vv2+1e-5f);
        s_hf[s][i] = y2*g2[1*256+i] + b2v[1*256+i];
        __syncthreads();
    }

    // ---- latent + gi0 ----
    if(tid<256){
        float a=0.f;
#pragma unroll
        for(int s=0;s<16;++s) a += s_hf[s][tid];
        latl[tid] = a*(1.0f/16.0f);
    }
    __syncthreads();
    for(int j=tid; j<768; j+=512){
        const float* wr = Wih + (size_t)j*256;
        float a = bih[j];
        for(int k=0;k<256;k+=4){
            float4 w4=*(const float4*)(wr+k);
            float4 l4=*(const float4*)&latl[k];
            a += w4.x*l4.x + w4.y*l4.y + w4.z*l4.z + w4.w*l4.w;
        }
        gi0l[j] = a;
    }
    __syncthreads();

    // anti-hoist fence: wf loads must not move above the prologue
    asm volatile("" ::: "memory");

    // ---- chain body (R9 verbatim) ----
    int l   = tid & 63;
    int w   = tid >> 6;
    int col = l & 15;
    int grp = l >> 4;
    int par = grp & 1;
    int ge  = w*32 + par*16 + col;

    const uint_t* Mdw = (const uint_t*)ws + WS_M8;
    v4i wf[8][4];
#pragma unroll
    for(int s=0;s<4;++s){
#pragma unroll
        for(int half=0; half<2; ++half){
            int f = s*2 + half;
            int row = s*256 + w*32 + half*16 + col;
            const uint_t* src = Mdw + (size_t)row*64 + grp*4;
#pragma unroll
            for(int kt=0;kt<4;++kt)
                wf[f][kt] = *(const v4i*)(src + kt*16);
        }
    }
    float Cs[4], MSs[4];
#pragma unroll
    for(int s=0;s<4;++s){
        int row = s*256 + ge;
        Cs[s]  = ws[WS_CV + row];
        MSs[s] = ws[WS_MS + row];
    }

    float r0 = sigf(gi0l[ge]     + bhh[ge]);
    float z0 = sigf(gi0l[256+ge] + bhh[256+ge]);
    float n0 = tanh_fast(gi0l[512+ge] + r0*bhh[512+ge]);
    float hp = (1.0f-z0)*n0;

    float* hsp = ws + WS_HSEQ + (size_t)b*256;
    if(grp < 2){
        h8[0][w*32 + (l&31)] = (signed char)__float2int_rn(hp*127.0f);
        hsp[w*32 + (l&31)] = hp;
    }
    asm volatile("s_waitcnt lgkmcnt(0)" ::: "memory");
    __builtin_amdgcn_s_barrier();
    asm volatile("" ::: "memory");

    const v4i vzero = {0,0,0,0};
    int po = 0;
    for(int t=1; t<1028; ++t){
        hsp += 4096;
        v4i af[4];
#pragma unroll
        for(int kt=0;kt<4;++kt)
            af[kt] = *(const v4i*)&h8[po][kt*64 + grp*16];
        v4i acc[8];
#pragma unroll
        for(int f=0;f<8;++f){
            acc[f] = __builtin_amdgcn_mfma_i32_16x16x64_i8(af[0], wf[f][0], vzero, 0,0,0);
#pragma unroll
            for(int kt=1;kt<4;++kt)
                acc[f] = __builtin_amdgcn_mfma_i32_16x16x64_i8(af[kt], wf[f][kt], acc[f], 0,0,0);
        }
        int a_r = par ? acc[1][0] : acc[0][0];
        int a_z = par ? acc[3][0] : acc[2][0];
        int a_n = par ? acc[5][0] : acc[4][0];
        int a_h = par ? acc[7][0] : acc[6][0];
        float yr = MSs[0]*(float)a_r + Cs[0];
        float yz = MSs[1]*(float)a_z + Cs[1];
        float yn = MSs[2]*(float)a_n + Cs[2];
        float yh = MSs[3]*(float)a_h + Cs[3];
        float rr = sigf(yr);
        float zz = sigf(yz);
        float nn = tanh_fast(yn + rr*yh);
        hp = (1.0f-zz)*nn + zz*hp;
        if(grp < 2){
            h8[po^1][w*32 + (l&31)] = (signed char)__float2int_rn(hp*127.0f);
            hsp[w*32 + (l&31)] = hp;
        }
        asm volatile("s_waitcnt lgkmcnt(0)" ::: "memory");
        __builtin_amdgcn_s_barrier();
        asm volatile("" ::: "memory");
        po ^= 1;
    }
}

// ======================= L5: epilogue GEMM (wide) ==========================

__global__ __launch_bounds__(256) void k_epi(const float* outW, const float* outb,
                                             const float* ws, float* out){
    __shared__ float ht[16][256];
    int t = blockIdx.x, j = threadIdx.x;
    for(int idx=j; idx<4096; idx+=256)
        ht[idx>>8][idx&255] = ws[WS_HSEQ + (size_t)t*4096 + idx];
    __syncthreads();
    const float* wr = outW + (size_t)j*256;
    float bias = outb[j];
    float acc[16];
#pragma unroll
    for(int bb=0;bb<16;++bb) acc[bb]=bias;
    for(int k=0;k<256;k+=4){
        float4 w4 = *(const float4*)(wr+k);
#pragma unroll
        for(int bb=0;bb<16;++bb)
            acc[bb] += w4.x*ht[bb][k]+w4.y*ht[bb][k+1]+w4.z*ht[bb][k+2]+w4.w*ht[bb][k+3];
    }
#pragma unroll
    for(int bb=0;bb<16;++bb)
        out[(size_t)bb*263168 + (size_t)t*256 + j] = acc[bb];
}

// ======================= launch ============================================

extern "C" void kernel_launch(void* const* d_in, const int* in_sizes, int n_in,
                              void* d_out, int out_size, void* d_ws, size_t ws_size,
                              hipStream_t stream){
    const float* gs   = (const float*)d_in[0];
    const float* eW   = (const float*)d_in[1];
    const float* eb   = (const float*)d_in[2];
    const float* qkvW = (const float*)d_in[3];
    const float* qkvb = (const float*)d_in[4];
    const float* aoW  = (const float*)d_in[5];
    const float* aob  = (const float*)d_in[6];
    const float* g1   = (const float*)d_in[7];
    const float* b1   = (const float*)d_in[8];
    const float* g2   = (const float*)d_in[9];
    const float* b2   = (const float*)d_in[10];
    const float* W1   = (const float*)d_in[11];
    const float* fb1  = (const float*)d_in[12];
    const float* W2   = (const float*)d_in[13];
    const float* fb2  = (const float*)d_in[14];
    const float* Wih  = (const float*)d_in[15];
    const float* Whh  = (const float*)d_in[16];
    const float* bih  = (const float*)d_in[17];
    const float* bhh  = (const float*)d_in[18];
    const float* outW = (const float*)d_in[19];
    const float* outb = (const float*)d_in[20];
    float* ws  = (float*)d_ws;
    float* out = (float*)d_out;

    k_pre     <<<1088,256,0,stream>>>(gs,eW,eb,qkvW,qkvb,Wih,Whh,bih,bhh,outW,outb,ws);
    k_ao_ffn  <<<256,256,0,stream>>>(aoW,aob,g1,b1,W1,fb1,W2,fb2,g2,b2,ws,0);
    k_qkv_attn<<<64,256,0,stream>>>(qkvW,qkvb,ws,1);
    k_chain   <<<16,512,0,stream>>>(aoW,aob,g1,b1,W1,fb1,W2,fb2,g2,b2,Wih,bih,bhh,ws);
    k_epi     <<<1028,256,0,stream>>>(outW,outb,ws,out);
}